// Round 5
// baseline (285.269 us; speedup 1.0000x reference)
//
#include <hip/hip_runtime.h>

// Propagation: E = softsign(V V^T / sqrt(D)); out0 = E @ state; out1 = E @ V
// B=4, N=4096, D=256, fp32 in/out.
//
// Round 5: AITER-style K-loop — B-operands of BOTH GEMMs read directly from
// global (L2/L3-resident bf16 Vb / VT written by the prepass) into registers
// as 16B-contiguous fragments. No vj/vjt LDS staging, no global_load_lds,
// no vmcnt(0) barrier drains. LDS only holds Esh (C->A layout round-trip for
// E) + reduction scratch. 2 lgkm-only barriers/iter. 512-thread blocks,
// 2 wave-groups splitting the j range, in-block final reduce (round 4).
//  - fallback: round-1 fused kernel if ws too small.

#define B_  4
#define N_  4096
#define D_  256

typedef __attribute__((ext_vector_type(8))) short short8;
typedef __attribute__((ext_vector_type(4))) float floatx4;

__device__ __forceinline__ unsigned short f2bf(float f) {
    unsigned int u = __float_as_uint(f);
    u += 0x7fff + ((u >> 16) & 1);   // RTNE
    return (unsigned short)(u >> 16);
}

// ---------------- pre-pass: fp32 -> bf16, plus transpose ----------------
__global__ __launch_bounds__(256)
void prepass_kernel(const float* __restrict__ val,
                    unsigned short* __restrict__ Vb,
                    unsigned short* __restrict__ VT) {
    __shared__ unsigned short tile[64][68];
    const int t   = threadIdx.x;
    const int blk = blockIdx.x;            // b*256 + it*4 + dt
    const int b   = blk >> 8;
    const int it  = (blk >> 2) & 63;
    const int dt  = blk & 3;
    const int i0  = it * 64, d0 = dt * 64;
    const float*    vb  = val + (size_t)b * N_ * D_;
    unsigned short* Vbb = Vb  + (size_t)b * N_ * D_;
    unsigned short* VTb = VT  + (size_t)b * D_ * N_;

    #pragma unroll
    for (int q = 0; q < 4; ++q) {
        int idx = t + 256 * q;
        int row = idx >> 4;
        int c4  = idx & 15;
        float4 v = *(const float4*)(vb + (size_t)(i0 + row) * D_ + d0 + c4 * 4);
        ushort4 h;
        h.x = f2bf(v.x); h.y = f2bf(v.y); h.z = f2bf(v.z); h.w = f2bf(v.w);
        *(ushort4*)(Vbb + (size_t)(i0 + row) * D_ + d0 + c4 * 4) = h;
        *(ushort4*)&tile[row][c4 * 4] = h;
    }
    __syncthreads();
    #pragma unroll
    for (int q = 0; q < 4; ++q) {
        int dr = (t >> 4) + q * 16;
        int i4 = t & 15;
        ushort4 h;
        h.x = tile[i4 * 4 + 0][dr];
        h.y = tile[i4 * 4 + 1][dr];
        h.z = tile[i4 * 4 + 2][dr];
        h.w = tile[i4 * 4 + 3][dr];
        *(ushort4*)(VTb + (size_t)(d0 + dr) * N_ + i0 + i4 * 4) = h;
    }
}

// ---------------- main fused kernel: 512 threads, 2 wave-groups ----------------
// LDS layout (67584 B total):
//   [0, 66560)            : dvred f32 [64][260] (epilogue overlay)
//     inside it, per group g (offset g*16384):
//       Esh_g : 64 x 72 bf16 = 9216 B    (live only during the loop)
//   [66560, 67584)        : dsred, 2 groups x 2 x 64 f32
__global__ __launch_bounds__(512, 1)
void prop_main(const float* __restrict__ state,
               const unsigned short* __restrict__ Vb,
               const unsigned short* __restrict__ VT,
               float* __restrict__ out) {
    __shared__ __attribute__((aligned(16))) unsigned char smem[67584];

    const int t    = threadIdx.x;
    const int g    = t >> 8;          // wave-group 0/1
    const int tg   = t & 255;
    const int w    = tg >> 6;         // wave within group, 0..3
    const int lane = t & 63;
    const int quad = lane >> 4;
    const int l16  = lane & 15;

    unsigned short* Eshg   = (unsigned short*)(smem + g * 16384);
    float*          dsredg = (float*)(smem + 66560 + g * 512);
    float*          dvred  = (float*)smem;

    const int b   = blockIdx.x >> 6;
    const int it0 = (blockIdx.x & 63) << 6;
    const int jbase = g * 2048;
    const int niter = 32;

    const unsigned short* Vbb = Vb + (size_t)b * N_ * D_;
    const unsigned short* VTb = VT + (size_t)b * D_ * N_;
    const float*          stb = state + (size_t)b * N_;

    const int r0 = (w >> 1) * 32;     // GEMM1 row base
    const int c0 = (w & 1) * 32;      // GEMM1 col (j) base

    // ---- hoist GEMM1 A-fragments to registers (loop-invariant) ----
    short8 A0[8], A1[8];
    {
        const unsigned short* ar0 = Vbb + (size_t)(it0 + r0 + l16) * 256 + quad * 8;
        const unsigned short* ar1 = ar0 + 16 * 256;
        #pragma unroll
        for (int ks = 0; ks < 8; ++ks) {
            A0[ks] = *(const short8*)(ar0 + ks * 32);
            A1[ks] = *(const short8*)(ar1 + ks * 32);
        }
    }

    // loop-invariant global bases for B-fragments
    const unsigned short* gb0 = Vbb + (size_t)(jbase + c0 + l16) * 256 + quad * 8;  // GEMM1 B rows
    const unsigned short* gb1 = gb0 + 16 * 256;
    const unsigned short* gt  = VTb + (size_t)jbase + quad * 8;                     // GEMM2 B (VT rows)

    floatx4 dv[4][4];
    #pragma unroll
    for (int a = 0; a < 4; ++a)
        #pragma unroll
        for (int c = 0; c < 4; ++c)
            dv[a][c] = (floatx4){0.f, 0.f, 0.f, 0.f};
    float dsp[8];
    #pragma unroll
    for (int k = 0; k < 8; ++k) dsp[k] = 0.f;

    for (int k = 0; k < niter; ++k) {
        const int j0 = k * 64;                 // within this group's range

        // ---- GEMM1 B-fragments: burst of 16 global b128 loads ----
        short8 Bf0[8], Bf1[8];
        {
            const unsigned short* p0 = gb0 + (size_t)j0 * 256;
            const unsigned short* p1 = gb1 + (size_t)j0 * 256;
            #pragma unroll
            for (int ks = 0; ks < 8; ++ks) {
                Bf0[ks] = *(const short8*)(p0 + ks * 32);
                Bf1[ks] = *(const short8*)(p1 + ks * 32);
            }
        }
        // state scalars for this j-tile (L1-hot)
        float stc0 = stb[jbase + j0 + c0 + l16];
        float stc1 = stb[jbase + j0 + c0 + 16 + l16];

        // ---- GEMM1: S = Vi . Vj^T (K = 256) ----
        floatx4 sa[2][2];
        #pragma unroll
        for (int a = 0; a < 2; ++a)
            #pragma unroll
            for (int c = 0; c < 2; ++c)
                sa[a][c] = (floatx4){0.f, 0.f, 0.f, 0.f};

        #pragma unroll
        for (int ks = 0; ks < 8; ++ks) {
            sa[0][0] = __builtin_amdgcn_mfma_f32_16x16x32_bf16(A0[ks], Bf0[ks], sa[0][0], 0, 0, 0);
            sa[0][1] = __builtin_amdgcn_mfma_f32_16x16x32_bf16(A0[ks], Bf1[ks], sa[0][1], 0, 0, 0);
            sa[1][0] = __builtin_amdgcn_mfma_f32_16x16x32_bf16(A1[ks], Bf0[ks], sa[1][0], 0, 0, 0);
            sa[1][1] = __builtin_amdgcn_mfma_f32_16x16x32_bf16(A1[ks], Bf1[ks], sa[1][1], 0, 0, 0);
        }

        // ---- softsign epilogue -> Esh + delta_state partials ----
        #pragma unroll
        for (int a = 0; a < 2; ++a) {
            #pragma unroll
            for (int r = 0; r < 4; ++r) {
                const int il = r0 + a * 16 + quad * 4 + r;
                float s0 = sa[a][0][r] * 0.0625f;
                float s1 = sa[a][1][r] * 0.0625f;
                float e0 = s0 * __builtin_amdgcn_rcpf(1.0f + fabsf(s0));
                float e1 = s1 * __builtin_amdgcn_rcpf(1.0f + fabsf(s1));
                dsp[a * 4 + r] += e0 * stc0 + e1 * stc1;
                Eshg[il * 72 + c0 + l16]      = f2bf(e0);
                Eshg[il * 72 + c0 + 16 + l16] = f2bf(e1);
            }
        }
        __syncthreads();   // B2: Esh visible (lgkm-only drain)

        // ---- GEMM2: dval += E . Vj  (B-fragments direct from VT global) ----
        short8 bfr[2][4];
        {
            const unsigned short* tp = gt + j0;
            #pragma unroll
            for (int ks = 0; ks < 2; ++ks)
                #pragma unroll
                for (int c2 = 0; c2 < 4; ++c2)
                    bfr[ks][c2] = *(const short8*)(tp + (size_t)(w * 64 + c2 * 16 + l16) * 4096 + ks * 32);
        }
        #pragma unroll
        for (int ks = 0; ks < 2; ++ks) {
            short8 af[4];
            #pragma unroll
            for (int a2 = 0; a2 < 4; ++a2)
                af[a2] = *(const short8*)&Eshg[(a2 * 16 + l16) * 72 + ks * 32 + quad * 8];
            #pragma unroll
            for (int a2 = 0; a2 < 4; ++a2)
                #pragma unroll
                for (int c2 = 0; c2 < 4; ++c2)
                    dv[a2][c2] = __builtin_amdgcn_mfma_f32_16x16x32_bf16(af[a2], bfr[ks][c2], dv[a2][c2], 0, 0, 0);
        }
        __syncthreads();   // B3: Esh reads done before next iter's writes
    }

    // ---- delta_state per-group reduction ----
    #pragma unroll
    for (int k = 0; k < 8; ++k) {
        float v = dsp[k];
        v += __shfl_xor(v, 1);
        v += __shfl_xor(v, 2);
        v += __shfl_xor(v, 4);
        v += __shfl_xor(v, 8);
        dsp[k] = v;
    }
    if (l16 == 0) {
        #pragma unroll
        for (int a = 0; a < 2; ++a)
            #pragma unroll
            for (int r = 0; r < 4; ++r) {
                const int row = (w >> 1) * 32 + a * 16 + quad * 4 + r;
                dsredg[(w & 1) * 64 + row] = dsp[a * 4 + r];
            }
    }
    __syncthreads();   // loop Esh dead; dsred visible after next barrier below

    // ---- group 1 dumps dv into LDS (overlays both Esh regions) ----
    if (g == 1) {
        #pragma unroll
        for (int a2 = 0; a2 < 4; ++a2)
            #pragma unroll
            for (int c2 = 0; c2 < 4; ++c2)
                #pragma unroll
                for (int r = 0; r < 4; ++r) {
                    const int i = a2 * 16 + quad * 4 + r;
                    const int d = w * 64 + c2 * 16 + l16;
                    dvred[i * 260 + d] = dv[a2][c2][r];
                }
    }
    __syncthreads();   // dvred + dsred visible

    if (g == 0) {
        // ---- final delta_val: dv(group0) + dvred(group1) -> out ----
        float* dvo = out + (size_t)B_ * N_ + (size_t)b * N_ * D_;
        #pragma unroll
        for (int a2 = 0; a2 < 4; ++a2)
            #pragma unroll
            for (int c2 = 0; c2 < 4; ++c2)
                #pragma unroll
                for (int r = 0; r < 4; ++r) {
                    const int il = a2 * 16 + quad * 4 + r;
                    const int d  = w * 64 + c2 * 16 + l16;
                    dvo[(size_t)(it0 + il) * D_ + d] = dv[a2][c2][r] + dvred[il * 260 + d];
                }
        // ---- final delta_state: sum the 4 dsred arrays ----
        if (t < 64) {
            const float* ds0 = (const float*)(smem + 66560);
            const float* ds1 = (const float*)(smem + 66560 + 512);
            out[(size_t)b * N_ + it0 + t] = ds0[t] + ds0[64 + t] + ds1[t] + ds1[64 + t];
        }
    }
}

// ---------------- fallback (round-1 kernel, used if ws too small) ----------------
__global__ __launch_bounds__(256, 1)
void prop_kernel_fb(const float* __restrict__ val,
                    const float* __restrict__ state,
                    float* __restrict__ out) {
    __shared__ __attribute__((aligned(16))) unsigned short vi[64][264];
    __shared__ __attribute__((aligned(16))) unsigned short vj[64][264];
    __shared__ __attribute__((aligned(16))) unsigned short vjt[2048][8];
    __shared__ __attribute__((aligned(16))) unsigned short Esh[64][72];
    __shared__ float stj[64];
    __shared__ float dsred[2][64];

    const int t    = threadIdx.x;
    const int w    = t >> 6;
    const int lane = t & 63;
    const int quad = lane >> 4;
    const int l16  = lane & 15;
    const int b   = blockIdx.x >> 6;
    const int it0 = (blockIdx.x & 63) << 6;
    const float* valb = val   + (size_t)b * N_ * D_;
    const float* stb  = state + (size_t)b * N_;

    #pragma unroll
    for (int n = 0; n < 16; ++n) {
        int idx = t + 256 * n;
        int row = idx >> 6;
        int c4  = idx & 63;
        float4 v = *(const float4*)(valb + (size_t)(it0 + row) * D_ + c4 * 4);
        ushort4 h;
        h.x = f2bf(v.x); h.y = f2bf(v.y); h.z = f2bf(v.z); h.w = f2bf(v.w);
        *(ushort4*)&vi[row][c4 * 4] = h;
    }

    const int r0 = (w >> 1) * 32;
    const int c0 = (w & 1) * 32;
    floatx4 dv[4][4];
    #pragma unroll
    for (int a = 0; a < 4; ++a)
        #pragma unroll
        for (int c = 0; c < 4; ++c)
            dv[a][c] = (floatx4){0.f, 0.f, 0.f, 0.f};
    float dsp[8];
    #pragma unroll
    for (int k = 0; k < 8; ++k) dsp[k] = 0.f;

    for (int jt = 0; jt < 64; ++jt) {
        const int j0 = jt * 64;
        #pragma unroll
        for (int n = 0; n < 16; ++n) {
            int idx = t + 256 * n;
            int row = idx >> 6;
            int c4  = idx & 63;
            float4 v = *(const float4*)(valb + (size_t)(j0 + row) * D_ + c4 * 4);
            ushort4 h;
            h.x = f2bf(v.x); h.y = f2bf(v.y); h.z = f2bf(v.z); h.w = f2bf(v.w);
            *(ushort4*)&vj[row][c4 * 4] = h;
        }
        if (t < 64) stj[t] = stb[j0 + t];
        __syncthreads();

        #pragma unroll
        for (int n = 0; n < 8; ++n) {
            const int d  = t;
            const int jb = n;
            short8 pk;
            #pragma unroll
            for (int jj = 0; jj < 8; ++jj) pk[jj] = (short)vj[jb * 8 + jj][d];
            *(short8*)&vjt[d * 8 + (jb ^ (d & 7))][0] = pk;
        }

        floatx4 sa[2][2];
        #pragma unroll
        for (int a = 0; a < 2; ++a)
            #pragma unroll
            for (int c = 0; c < 2; ++c)
                sa[a][c] = (floatx4){0.f, 0.f, 0.f, 0.f};
        #pragma unroll
        for (int ks = 0; ks < 8; ++ks) {
            const int d0 = ks * 32 + quad * 8;
            short8 a0 = *(const short8*)&vi[r0 + l16][d0];
            short8 a1 = *(const short8*)&vi[r0 + 16 + l16][d0];
            short8 b0 = *(const short8*)&vj[c0 + l16][d0];
            short8 b1 = *(const short8*)&vj[c0 + 16 + l16][d0];
            sa[0][0] = __builtin_amdgcn_mfma_f32_16x16x32_bf16(a0, b0, sa[0][0], 0, 0, 0);
            sa[0][1] = __builtin_amdgcn_mfma_f32_16x16x32_bf16(a0, b1, sa[0][1], 0, 0, 0);
            sa[1][0] = __builtin_amdgcn_mfma_f32_16x16x32_bf16(a1, b0, sa[1][0], 0, 0, 0);
            sa[1][1] = __builtin_amdgcn_mfma_f32_16x16x32_bf16(a1, b1, sa[1][1], 0, 0, 0);
        }

        float stc0 = stj[c0 + l16];
        float stc1 = stj[c0 + 16 + l16];
        #pragma unroll
        for (int a = 0; a < 2; ++a) {
            #pragma unroll
            for (int r = 0; r < 4; ++r) {
                const int il = r0 + a * 16 + quad * 4 + r;
                float s0 = sa[a][0][r] * 0.0625f;
                float s1 = sa[a][1][r] * 0.0625f;
                float e0 = s0 / (1.0f + fabsf(s0));
                float e1 = s1 / (1.0f + fabsf(s1));
                dsp[a * 4 + r] += e0 * stc0 + e1 * stc1;
                Esh[il][c0 + l16]      = f2bf(e0);
                Esh[il][c0 + 16 + l16] = f2bf(e1);
            }
        }
        __syncthreads();

        #pragma unroll
        for (int ks = 0; ks < 2; ++ks) {
            short8 af[4], bfr[4];
            #pragma unroll
            for (int a2 = 0; a2 < 4; ++a2)
                af[a2] = *(const short8*)&Esh[a2 * 16 + l16][ks * 32 + quad * 8];
            #pragma unroll
            for (int c2 = 0; c2 < 4; ++c2) {
                const int d  = w * 64 + c2 * 16 + l16;
                const int jb = ks * 4 + quad;
                bfr[c2] = *(const short8*)&vjt[d * 8 + (jb ^ (d & 7))][0];
            }
            #pragma unroll
            for (int a2 = 0; a2 < 4; ++a2)
                #pragma unroll
                for (int c2 = 0; c2 < 4; ++c2)
                    dv[a2][c2] = __builtin_amdgcn_mfma_f32_16x16x32_bf16(af[a2], bfr[c2], dv[a2][c2], 0, 0, 0);
        }
    }

    float* dvo = out + (size_t)B_ * N_ + (size_t)b * N_ * D_;
    #pragma unroll
    for (int a2 = 0; a2 < 4; ++a2)
        #pragma unroll
        for (int c2 = 0; c2 < 4; ++c2)
            #pragma unroll
            for (int r = 0; r < 4; ++r) {
                const int i = it0 + a2 * 16 + quad * 4 + r;
                const int d = w * 64 + c2 * 16 + l16;
                dvo[(size_t)i * D_ + d] = dv[a2][c2][r];
            }

    #pragma unroll
    for (int k = 0; k < 8; ++k) {
        float v = dsp[k];
        v += __shfl_xor(v, 1);
        v += __shfl_xor(v, 2);
        v += __shfl_xor(v, 4);
        v += __shfl_xor(v, 8);
        dsp[k] = v;
    }
    if (l16 == 0) {
        #pragma unroll
        for (int a = 0; a < 2; ++a)
            #pragma unroll
            for (int r = 0; r < 4; ++r) {
                const int row = (w >> 1) * 32 + a * 16 + quad * 4 + r;
                dsred[w & 1][row] = dsp[a * 4 + r];
            }
    }
    __syncthreads();
    if (t < 64) out[(size_t)b * N_ + it0 + t] = dsred[0][t] + dsred[1][t];
}

extern "C" void kernel_launch(void* const* d_in, const int* in_sizes, int n_in,
                              void* d_out, int out_size, void* d_ws, size_t ws_size,
                              hipStream_t stream) {
    const float* val   = (const float*)d_in[0];
    const float* state = (const float*)d_in[1];
    float* out = (float*)d_out;

    const size_t nE   = (size_t)B_ * N_ * D_;              // 4,194,304
    const size_t need = 2 * nE * sizeof(unsigned short);   // 16.78 MB

    if (ws_size >= need) {
        unsigned short* Vb = (unsigned short*)d_ws;
        unsigned short* VT = Vb + nE;
        prepass_kernel<<<dim3(1024), dim3(256), 0, stream>>>(val, Vb, VT);
        prop_main<<<dim3(256), dim3(512), 0, stream>>>(state, Vb, VT, out);
    } else {
        prop_kernel_fb<<<dim3(256), dim3(256), 0, stream>>>(val, state, out);
    }
}

// Round 6
// 150.996 us; speedup vs baseline: 1.8892x; 1.8892x over previous
//
#include <hip/hip_runtime.h>

// Propagation: E = softsign(V V^T / sqrt(D)); out0 = E @ state; out1 = E @ V
// B=4, N=4096, D=256, fp32 in/out.
//
// Round 6:
//  - prepass: val fp32 -> Vb bf16 [B][N][D] and VT bf16 [B][D][N] in d_ws.
//  - main: 512 threads = 2 wave-groups splitting the *i* range (128 rows per
//    block); both groups SHARE the j-tile (vj/vjt staged once per iter for 2x
//    the FLOPs -> staging per FLOP halves vs R4). LDS: vjt double-buffered
//    (staged at top of iter -> ~full-GEMM1 latency window), vj single
//    (staged after B2, window = GEMM2), Esh double-buffered (kills the 3rd
//    barrier). 2 barriers/iter. j is split across BLOCKS (grid 256 = b x
//    32 i-tiles x 2 j-halves); partial dv/ds in ws; combine kernel (R3).
//  - softsign folded: e = s/(16+|s|)  (== (s/16)/(1+|s/16|)).
//  - fallback: round-1 fused kernel if ws too small.

#define B_  4
#define N_  4096
#define D_  256

typedef __attribute__((ext_vector_type(8))) short short8;
typedef __attribute__((ext_vector_type(4))) float floatx4;

__device__ __forceinline__ unsigned short f2bf(float f) {
    unsigned int u = __float_as_uint(f);
    u += 0x7fff + ((u >> 16) & 1);   // RTNE
    return (unsigned short)(u >> 16);
}

__device__ __forceinline__ void gl_lds16(const void* g, void* l) {
    __builtin_amdgcn_global_load_lds(
        (const __attribute__((address_space(1))) unsigned int*)g,
        (__attribute__((address_space(3))) unsigned int*)l, 16, 0, 0);
}
__device__ __forceinline__ void gl_lds4(const void* g, void* l) {
    __builtin_amdgcn_global_load_lds(
        (const __attribute__((address_space(1))) unsigned int*)g,
        (__attribute__((address_space(3))) unsigned int*)l, 4, 0, 0);
}

// ---------------- pre-pass: fp32 -> bf16, plus transpose ----------------
__global__ __launch_bounds__(256)
void prepass_kernel(const float* __restrict__ val,
                    unsigned short* __restrict__ Vb,
                    unsigned short* __restrict__ VT) {
    __shared__ unsigned short tile[64][68];
    const int t   = threadIdx.x;
    const int blk = blockIdx.x;            // b*256 + it*4 + dt
    const int b   = blk >> 8;
    const int it  = (blk >> 2) & 63;
    const int dt  = blk & 3;
    const int i0  = it * 64, d0 = dt * 64;
    const float*    vb  = val + (size_t)b * N_ * D_;
    unsigned short* Vbb = Vb  + (size_t)b * N_ * D_;
    unsigned short* VTb = VT  + (size_t)b * D_ * N_;

    #pragma unroll
    for (int q = 0; q < 4; ++q) {
        int idx = t + 256 * q;
        int row = idx >> 4;
        int c4  = idx & 15;
        float4 v = *(const float4*)(vb + (size_t)(i0 + row) * D_ + d0 + c4 * 4);
        ushort4 h;
        h.x = f2bf(v.x); h.y = f2bf(v.y); h.z = f2bf(v.z); h.w = f2bf(v.w);
        *(ushort4*)(Vbb + (size_t)(i0 + row) * D_ + d0 + c4 * 4) = h;
        *(ushort4*)&tile[row][c4 * 4] = h;
    }
    __syncthreads();
    #pragma unroll
    for (int q = 0; q < 4; ++q) {
        int dr = (t >> 4) + q * 16;
        int i4 = t & 15;
        ushort4 h;
        h.x = tile[i4 * 4 + 0][dr];
        h.y = tile[i4 * 4 + 1][dr];
        h.z = tile[i4 * 4 + 2][dr];
        h.w = tile[i4 * 4 + 3][dr];
        *(ushort4*)(VTb + (size_t)(d0 + dr) * N_ + i0 + i4 * 4) = h;
    }
}

// ---------------- main fused kernel ----------------
// grid 256 = b(4) x it(32, 128-row tiles) x jh(2).  512 threads:
// group g = i-rows [it0+g*64, it0+g*64+64); both groups share the j-tile.
// LDS map (bytes), total 136448:
//   vjt  : 0      + buf*32768   (2 x 32768)  [256 d][64 j] granule-swizzled
//   vj   : 65536               (32768)       [64 j][256 d] granule-swizzled
//   Esh  : 98304  + g*18432 + buf*9216       (2 g x 2 buf x 64 x 72 bf16)
//   stj  : 135168              (256)         64 f32
//   dsred: 135424 + g*512      (2 x 512)     [2][64] f32 per group
__global__ __launch_bounds__(512, 1)
void prop_main(const float* __restrict__ state,
               const unsigned short* __restrict__ Vb,
               const unsigned short* __restrict__ VT,
               float* __restrict__ dvp,   // [2][B][N][D] partials
               float* __restrict__ dsp_o) // [2][B][N]    partials
{
    __shared__ __attribute__((aligned(16))) unsigned char smem[136448];

    const int t    = threadIdx.x;
    const int g    = t >> 8;          // wave-group (i-half) 0/1
    const int w    = t >> 6;          // wave 0..7
    const int w4   = w & 3;           // wave within group
    const int lane = t & 63;
    const int quad = lane >> 4;
    const int l16  = lane & 15;

    const int x   = blockIdx.x;
    const int b   = x >> 6;
    const int it  = (x >> 1) & 31;
    const int jh  = x & 1;
    const int it0 = it * 128;
    const int jbase = jh * 2048;
    const int niter = 32;

    unsigned short* vjL  = (unsigned short*)(smem + 65536);
    unsigned short* stjL_= (unsigned short*)(smem + 135168);  // as f32 below
    float*          stjL = (float*)stjL_;
    float*          dsredg = (float*)(smem + 135424 + g * 512);

    const unsigned short* Vbb = Vb + (size_t)b * N_ * D_;
    const unsigned short* VTb = VT + (size_t)b * D_ * N_;
    const float*          stb = state + (size_t)b * N_;

    const int hi  = lane >> 5;
    const int p32 = lane & 31;
    const int dr8 = lane >> 3;
    const int p8  = lane & 7;

    // per-wave staging offsets (8 waves cooperatively stage the shared tile)
    int vgoff[4];   // vj: rows 2*(w*4+n)+hi, granule-swizzled
    int tgoff[4];   // vjt: d-rows 8*(w*4+n)+dr8
    #pragma unroll
    for (int n = 0; n < 4; ++n) {
        int r  = 2 * (w * 4 + n) + hi;           // 0..63
        int gr = p32 ^ (r & 7);
        vgoff[n] = r * 256 + gr * 8;
        int d  = 8 * (w * 4 + n) + dr8;          // 0..255
        int gt = p8 ^ dr8;                        // == p8 ^ (d&7)
        tgoff[n] = d * 4096 + gt * 8;
    }

    const int r0 = (w4 >> 1) * 32;    // GEMM1 row base within group
    const int c0 = (w4 & 1) * 32;     // GEMM1 col (j) base
    const int pA = l16 & 7;

    // ---- hoist GEMM1 A-fragments to registers (loop-invariant) ----
    short8 A0[8], A1[8];
    {
        const unsigned short* ar0 = Vbb + (size_t)(it0 + g * 64 + r0 + l16) * 256 + quad * 8;
        const unsigned short* ar1 = ar0 + 16 * 256;
        #pragma unroll
        for (int ks = 0; ks < 8; ++ks) {
            A0[ks] = *(const short8*)(ar0 + ks * 32);
            A1[ks] = *(const short8*)(ar1 + ks * 32);
        }
    }

    // ---- prologue: stage tile 0 (vjt->buf0, vj, stj) ----
    #pragma unroll
    for (int n = 0; n < 4; ++n)
        gl_lds16(VTb + (size_t)jbase + tgoff[n],
                 smem + (w * 4 + n) * 1024);
    #pragma unroll
    for (int n = 0; n < 4; ++n)
        gl_lds16(Vbb + (size_t)jbase * 256 + vgoff[n],
                 smem + 65536 + (w * 4 + n) * 1024);
    if (w == 0) gl_lds4(stb + jbase + lane, stjL);

    floatx4 dv[4][4];
    #pragma unroll
    for (int a = 0; a < 4; ++a)
        #pragma unroll
        for (int c = 0; c < 4; ++c)
            dv[a][c] = (floatx4){0.f, 0.f, 0.f, 0.f};
    float dsp[8];
    #pragma unroll
    for (int k = 0; k < 8; ++k) dsp[k] = 0.f;

    for (int k = 0; k < niter; ++k) {
        const int buf = k & 1;
        unsigned short* Eshg = (unsigned short*)(smem + 98304 + g * 18432 + buf * 9216);
        unsigned short* vjtg = (unsigned short*)(smem + buf * 32768);

        __syncthreads();   // B1: vjt[buf](k), vj(k), stj(k) visible

        // ---- stage vjt(k+1) into the other buffer (window: GEMM1+epilogue) ----
        if (k + 1 < niter) {
            const size_t j0n = jbase + (size_t)(k + 1) * 64;
            #pragma unroll
            for (int n = 0; n < 4; ++n)
                gl_lds16(VTb + j0n + tgoff[n],
                         smem + (buf ^ 1) * 32768 + (w * 4 + n) * 1024);
        }

        // ---- GEMM1: S = Vi . Vj^T (K=256, A from registers, B from vj) ----
        floatx4 sa[2][2];
        #pragma unroll
        for (int a = 0; a < 2; ++a)
            #pragma unroll
            for (int c = 0; c < 2; ++c)
                sa[a][c] = (floatx4){0.f, 0.f, 0.f, 0.f};

        #pragma unroll
        for (int ks = 0; ks < 8; ++ks) {
            const int p = ((ks * 4 + quad) ^ pA) * 8;
            short8 b0 = *(const short8*)&vjL[(c0 + l16) * 256 + p];
            short8 b1 = *(const short8*)&vjL[(c0 + 16 + l16) * 256 + p];
            sa[0][0] = __builtin_amdgcn_mfma_f32_16x16x32_bf16(A0[ks], b0, sa[0][0], 0, 0, 0);
            sa[0][1] = __builtin_amdgcn_mfma_f32_16x16x32_bf16(A0[ks], b1, sa[0][1], 0, 0, 0);
            sa[1][0] = __builtin_amdgcn_mfma_f32_16x16x32_bf16(A1[ks], b0, sa[1][0], 0, 0, 0);
            sa[1][1] = __builtin_amdgcn_mfma_f32_16x16x32_bf16(A1[ks], b1, sa[1][1], 0, 0, 0);
        }

        // ---- softsign epilogue: e = s/(16+|s|) -> Esh[buf] + ds partials ----
        float stc0 = stjL[c0 + l16];
        float stc1 = stjL[c0 + 16 + l16];
        #pragma unroll
        for (int a = 0; a < 2; ++a) {
            #pragma unroll
            for (int r = 0; r < 4; ++r) {
                const int il = r0 + a * 16 + quad * 4 + r;
                float s0 = sa[a][0][r];
                float s1 = sa[a][1][r];
                float e0 = s0 * __builtin_amdgcn_rcpf(16.0f + fabsf(s0));
                float e1 = s1 * __builtin_amdgcn_rcpf(16.0f + fabsf(s1));
                dsp[a * 4 + r] += e0 * stc0 + e1 * stc1;
                Eshg[il * 72 + c0 + l16]      = f2bf(e0);
                Eshg[il * 72 + c0 + 16 + l16] = f2bf(e1);
            }
        }
        __syncthreads();   // B2: Esh[buf] visible; vj/stj reads drained; vjt(k+1) DMA drained

        // ---- stage vj(k+1)/stj(k+1) (single buffer; window: GEMM2) ----
        if (k + 1 < niter) {
            const size_t j0n = jbase + (size_t)(k + 1) * 64;
            #pragma unroll
            for (int n = 0; n < 4; ++n)
                gl_lds16(Vbb + j0n * 256 + vgoff[n],
                         smem + 65536 + (w * 4 + n) * 1024);
            if (w == 0) gl_lds4(stb + j0n + lane, stjL);
        }

        // ---- GEMM2: dval += E . Vj (A from Esh[buf], B from vjt[buf]) ----
        #pragma unroll
        for (int ks = 0; ks < 2; ++ks) {
            short8 af[4], bfr[4];
            #pragma unroll
            for (int a2 = 0; a2 < 4; ++a2)
                af[a2] = *(const short8*)&Eshg[(a2 * 16 + l16) * 72 + ks * 32 + quad * 8];
            #pragma unroll
            for (int c2 = 0; c2 < 4; ++c2) {
                const int d = w4 * 64 + c2 * 16 + l16;
                const int p = ((ks * 4 + quad) ^ (l16 & 7)) * 8;
                bfr[c2] = *(const short8*)&vjtg[d * 64 + p];
            }
            #pragma unroll
            for (int a2 = 0; a2 < 4; ++a2)
                #pragma unroll
                for (int c2 = 0; c2 < 4; ++c2)
                    dv[a2][c2] = __builtin_amdgcn_mfma_f32_16x16x32_bf16(af[a2], bfr[c2], dv[a2][c2], 0, 0, 0);
        }
        // next barrier is B1 of iter k+1
    }

    // ---- epilogue: partial delta_val for this (i-half, j-half) ----
    float* dvo = dvp + (size_t)jh * B_ * N_ * D_ + (size_t)b * N_ * D_
                     + (size_t)(it0 + g * 64) * D_;
    #pragma unroll
    for (int a2 = 0; a2 < 4; ++a2)
        #pragma unroll
        for (int c2 = 0; c2 < 4; ++c2)
            #pragma unroll
            for (int r = 0; r < 4; ++r) {
                const int il = a2 * 16 + quad * 4 + r;
                const int d  = w4 * 64 + c2 * 16 + l16;
                dvo[(size_t)il * D_ + d] = dv[a2][c2][r];
            }

    // ---- epilogue: partial delta_state ----
    #pragma unroll
    for (int k = 0; k < 8; ++k) {
        float v = dsp[k];
        v += __shfl_xor(v, 1);
        v += __shfl_xor(v, 2);
        v += __shfl_xor(v, 4);
        v += __shfl_xor(v, 8);
        dsp[k] = v;
    }
    if (l16 == 0) {
        #pragma unroll
        for (int a = 0; a < 2; ++a)
            #pragma unroll
            for (int r = 0; r < 4; ++r) {
                const int row = r0 + a * 16 + quad * 4 + r;
                dsredg[(w4 & 1) * 64 + row] = dsp[a * 4 + r];
            }
    }
    __syncthreads();
    if (t < 128) {
        const int gg  = t >> 6;
        const int row = t & 63;
        const float* dsr = (const float*)(smem + 135424 + gg * 512);
        dsp_o[(size_t)jh * B_ * N_ + (size_t)b * N_ + it0 + gg * 64 + row]
            = dsr[row] + dsr[64 + row];
    }
}

// ---------------- combine: out = sum of the two j-half partials ----------------
__global__ __launch_bounds__(256)
void combine_kernel(const float4* __restrict__ dv0, const float4* __restrict__ dv1,
                    const float*  __restrict__ ds0, const float*  __restrict__ ds1,
                    float* __restrict__ out) {
    const int NDV4 = B_ * N_ * D_ / 4;   // 1048576
    const int NDS  = B_ * N_;            // 16384
    int x = blockIdx.x * 256 + threadIdx.x;
    if (x < NDV4) {
        float4 a = dv0[x], c = dv1[x];
        float4 r;
        r.x = a.x + c.x; r.y = a.y + c.y; r.z = a.z + c.z; r.w = a.w + c.w;
        ((float4*)(out + NDS))[x] = r;
    } else {
        int y = (x - NDV4) * 4;
        if (y < NDS) {
            float4 a = *(const float4*)(ds0 + y);
            float4 c = *(const float4*)(ds1 + y);
            float4 r;
            r.x = a.x + c.x; r.y = a.y + c.y; r.z = a.z + c.z; r.w = a.w + c.w;
            *(float4*)(out + y) = r;
        }
    }
}

// ---------------- fallback (round-1 kernel, used if ws too small) ----------------
__global__ __launch_bounds__(256, 1)
void prop_kernel_fb(const float* __restrict__ val,
                    const float* __restrict__ state,
                    float* __restrict__ out) {
    __shared__ __attribute__((aligned(16))) unsigned short vi[64][264];
    __shared__ __attribute__((aligned(16))) unsigned short vj[64][264];
    __shared__ __attribute__((aligned(16))) unsigned short vjt[2048][8];
    __shared__ __attribute__((aligned(16))) unsigned short Esh[64][72];
    __shared__ float stj[64];
    __shared__ float dsred[2][64];

    const int t    = threadIdx.x;
    const int w    = t >> 6;
    const int lane = t & 63;
    const int quad = lane >> 4;
    const int l16  = lane & 15;
    const int b   = blockIdx.x >> 6;
    const int it0 = (blockIdx.x & 63) << 6;
    const float* valb = val   + (size_t)b * N_ * D_;
    const float* stb  = state + (size_t)b * N_;

    #pragma unroll
    for (int n = 0; n < 16; ++n) {
        int idx = t + 256 * n;
        int row = idx >> 6;
        int c4  = idx & 63;
        float4 v = *(const float4*)(valb + (size_t)(it0 + row) * D_ + c4 * 4);
        ushort4 h;
        h.x = f2bf(v.x); h.y = f2bf(v.y); h.z = f2bf(v.z); h.w = f2bf(v.w);
        *(ushort4*)&vi[row][c4 * 4] = h;
    }

    const int r0 = (w >> 1) * 32;
    const int c0 = (w & 1) * 32;
    floatx4 dv[4][4];
    #pragma unroll
    for (int a = 0; a < 4; ++a)
        #pragma unroll
        for (int c = 0; c < 4; ++c)
            dv[a][c] = (floatx4){0.f, 0.f, 0.f, 0.f};
    float dsp[8];
    #pragma unroll
    for (int k = 0; k < 8; ++k) dsp[k] = 0.f;

    for (int jt = 0; jt < 64; ++jt) {
        const int j0 = jt * 64;
        #pragma unroll
        for (int n = 0; n < 16; ++n) {
            int idx = t + 256 * n;
            int row = idx >> 6;
            int c4  = idx & 63;
            float4 v = *(const float4*)(valb + (size_t)(j0 + row) * D_ + c4 * 4);
            ushort4 h;
            h.x = f2bf(v.x); h.y = f2bf(v.y); h.z = f2bf(v.z); h.w = f2bf(v.w);
            *(ushort4*)&vj[row][c4 * 4] = h;
        }
        if (t < 64) stj[t] = stb[j0 + t];
        __syncthreads();

        #pragma unroll
        for (int n = 0; n < 8; ++n) {
            const int d  = t;
            const int jb = n;
            short8 pk;
            #pragma unroll
            for (int jj = 0; jj < 8; ++jj) pk[jj] = (short)vj[jb * 8 + jj][d];
            *(short8*)&vjt[d * 8 + (jb ^ (d & 7))][0] = pk;
        }

        floatx4 sa[2][2];
        #pragma unroll
        for (int a = 0; a < 2; ++a)
            #pragma unroll
            for (int c = 0; c < 2; ++c)
                sa[a][c] = (floatx4){0.f, 0.f, 0.f, 0.f};
        #pragma unroll
        for (int ks = 0; ks < 8; ++ks) {
            const int d0 = ks * 32 + quad * 8;
            short8 a0 = *(const short8*)&vi[r0 + l16][d0];
            short8 a1 = *(const short8*)&vi[r0 + 16 + l16][d0];
            short8 b0 = *(const short8*)&vj[c0 + l16][d0];
            short8 b1 = *(const short8*)&vj[c0 + 16 + l16][d0];
            sa[0][0] = __builtin_amdgcn_mfma_f32_16x16x32_bf16(a0, b0, sa[0][0], 0, 0, 0);
            sa[0][1] = __builtin_amdgcn_mfma_f32_16x16x32_bf16(a0, b1, sa[0][1], 0, 0, 0);
            sa[1][0] = __builtin_amdgcn_mfma_f32_16x16x32_bf16(a1, b0, sa[1][0], 0, 0, 0);
            sa[1][1] = __builtin_amdgcn_mfma_f32_16x16x32_bf16(a1, b1, sa[1][1], 0, 0, 0);
        }

        float stc0 = stj[c0 + l16];
        float stc1 = stj[c0 + 16 + l16];
        #pragma unroll
        for (int a = 0; a < 2; ++a) {
            #pragma unroll
            for (int r = 0; r < 4; ++r) {
                const int il = r0 + a * 16 + quad * 4 + r;
                float s0 = sa[a][0][r] * 0.0625f;
                float s1 = sa[a][1][r] * 0.0625f;
                float e0 = s0 / (1.0f + fabsf(s0));
                float e1 = s1 / (1.0f + fabsf(s1));
                dsp[a * 4 + r] += e0 * stc0 + e1 * stc1;
                Esh[il][c0 + l16]      = f2bf(e0);
                Esh[il][c0 + 16 + l16] = f2bf(e1);
            }
        }
        __syncthreads();

        #pragma unroll
        for (int ks = 0; ks < 2; ++ks) {
            short8 af[4], bfr[4];
            #pragma unroll
            for (int a2 = 0; a2 < 4; ++a2)
                af[a2] = *(const short8*)&Esh[a2 * 16 + l16][ks * 32 + quad * 8];
            #pragma unroll
            for (int c2 = 0; c2 < 4; ++c2) {
                const int d  = w * 64 + c2 * 16 + l16;
                const int jb = ks * 4 + quad;
                bfr[c2] = *(const short8*)&vjt[d * 8 + (jb ^ (d & 7))][0];
            }
            #pragma unroll
            for (int a2 = 0; a2 < 4; ++a2)
                #pragma unroll
                for (int c2 = 0; c2 < 4; ++c2)
                    dv[a2][c2] = __builtin_amdgcn_mfma_f32_16x16x32_bf16(af[a2], bfr[c2], dv[a2][c2], 0, 0, 0);
        }
    }

    float* dvo = out + (size_t)B_ * N_ + (size_t)b * N_ * D_;
    #pragma unroll
    for (int a2 = 0; a2 < 4; ++a2)
        #pragma unroll
        for (int c2 = 0; c2 < 4; ++c2)
            #pragma unroll
            for (int r = 0; r < 4; ++r) {
                const int i = it0 + a2 * 16 + quad * 4 + r;
                const int d = w * 64 + c2 * 16 + l16;
                dvo[(size_t)i * D_ + d] = dv[a2][c2][r];
            }

    #pragma unroll
    for (int k = 0; k < 8; ++k) {
        float v = dsp[k];
        v += __shfl_xor(v, 1);
        v += __shfl_xor(v, 2);
        v += __shfl_xor(v, 4);
        v += __shfl_xor(v, 8);
        dsp[k] = v;
    }
    if (l16 == 0) {
        #pragma unroll
        for (int a = 0; a < 2; ++a)
            #pragma unroll
            for (int r = 0; r < 4; ++r) {
                const int row = (w >> 1) * 32 + a * 16 + quad * 4 + r;
                dsred[w & 1][row] = dsp[a * 4 + r];
            }
    }
    __syncthreads();
    if (t < 64) out[(size_t)b * N_ + it0 + t] = dsred[0][t] + dsred[1][t];
}

extern "C" void kernel_launch(void* const* d_in, const int* in_sizes, int n_in,
                              void* d_out, int out_size, void* d_ws, size_t ws_size,
                              hipStream_t stream) {
    const float* val   = (const float*)d_in[0];
    const float* state = (const float*)d_in[1];
    float* out = (float*)d_out;

    const size_t nE         = (size_t)B_ * N_ * D_;                 // 4,194,304
    const size_t need_base  = 2 * nE * sizeof(unsigned short);      // 16.78 MB
    const size_t need_split = need_base + 2 * nE * sizeof(float)
                            + 2 * (size_t)B_ * N_ * sizeof(float);  // ~50.5 MB

    if (ws_size >= need_split) {
        unsigned short* Vb = (unsigned short*)d_ws;
        unsigned short* VT = Vb + nE;
        float* dvp = (float*)(VT + nE);          // [2][B*N*D]
        float* dsp = dvp + 2 * nE;               // [2][B*N]
        prepass_kernel<<<dim3(1024), dim3(256), 0, stream>>>(val, Vb, VT);
        prop_main<<<dim3(256), dim3(512), 0, stream>>>(state, Vb, VT, dvp, dsp);
        const int NDV4 = B_ * N_ * D_ / 4;
        const int NDS4 = B_ * N_ / 4;
        combine_kernel<<<dim3((NDV4 + NDS4) / 256), dim3(256), 0, stream>>>(
            (const float4*)dvp, (const float4*)(dvp + nE),
            dsp, dsp + (size_t)B_ * N_, out);
    } else {
        prop_kernel_fb<<<dim3(256), dim3(256), 0, stream>>>(val, state, out);
    }
}